// Round 4
// baseline (420.871 us; speedup 1.0000x reference)
//
#include <hip/hip_runtime.h>

#define B_  4
#define S_  2048
#define D_  1024
#define H_  16
#define DK_ 64

typedef __attribute__((ext_vector_type(8))) __bf16 bf16x8;
typedef __attribute__((ext_vector_type(4))) float  f32x4;
typedef __attribute__((ext_vector_type(4))) short  short4v;

#define AS1 __attribute__((address_space(1)))
#define AS3 __attribute__((address_space(3)))

// Async 16B global -> LDS. Per-lane dest must equal wave-uniform base + lane*16.
__device__ __forceinline__ void gl2lds16(const void* g, void* l) {
    __builtin_amdgcn_global_load_lds((const AS1 unsigned int*)g,
                                     (AS3 unsigned int*)l, 16, 0, 0);
}

__device__ __forceinline__ unsigned short f2bf(float f) {
    union { float f; unsigned u; } v; v.f = f;
    return (unsigned short)((v.u + 0x7FFFu + ((v.u >> 16) & 1u)) >> 16);
}

// pack bf16(f0) low | bf16(f1) high; round via +0x8000, v_perm pack.
__device__ __forceinline__ unsigned pk_bf16(float f0, float f1) {
    union { float f; unsigned u; } a, b; a.f = f0; b.f = f1;
    return __builtin_amdgcn_perm(b.u + 0x8000u, a.u + 0x8000u, 0x07060302u);
}

// hardware packed f32->bf16 (RNE), 1 VALU op for 2 values (T12 primitive)
__device__ __forceinline__ unsigned cvt_pk_bf16(float lo, float hi) {
    unsigned r;
    asm("v_cvt_pk_bf16_f32 %0, %1, %2" : "=v"(r) : "v"(lo), "v"(hi));
    return r;
}

__device__ __forceinline__ void cast8(const float* __restrict__ x,
                                      unsigned short* __restrict__ y, int i) {
    float4 a = ((const float4*)x)[2 * i];
    float4 b = ((const float4*)x)[2 * i + 1];
    uint4 w;
    w.x = pk_bf16(a.x, a.y);
    w.y = pk_bf16(a.z, a.w);
    w.z = pk_bf16(b.x, b.y);
    w.w = pk_bf16(b.z, b.w);
    ((uint4*)y)[i] = w;
}

// Merged fp32->bf16 casts: grid.y selects tensor (activations q,k,v).
__global__ __launch_bounds__(256) void cast_act(
    const float* __restrict__ a, const float* __restrict__ b,
    const float* __restrict__ c, unsigned short* __restrict__ ya,
    unsigned short* __restrict__ yb, unsigned short* __restrict__ yc)
{
    const int sel = blockIdx.y;
    const float* x = (sel == 0) ? a : (sel == 1) ? b : c;
    unsigned short* y = (sel == 0) ? ya : (sel == 1) ? yb : yc;
    cast8(x, y, blockIdx.x * 256 + threadIdx.x);
}

// Merged weight casts: grid.y in 0..3.
__global__ __launch_bounds__(256) void cast_w(
    const float* __restrict__ a, const float* __restrict__ b,
    const float* __restrict__ c, const float* __restrict__ d,
    unsigned short* __restrict__ ya, unsigned short* __restrict__ yb,
    unsigned short* __restrict__ yc, unsigned short* __restrict__ yd)
{
    const int sel = blockIdx.y;
    const float* x = (sel == 0) ? a : (sel == 1) ? b : (sel == 2) ? c : d;
    unsigned short* y = (sel == 0) ? ya : (sel == 1) ? yb : (sel == 2) ? yc : yd;
    cast8(x, y, blockIdx.x * 256 + threadIdx.x);
}

// Fused QKV projection GEMM over N=3072 output cols (Wq;Wk;Wv rows contiguous).
// CRITICAL (R7/R8 bug): each projection has a DIFFERENT A-operand —
// Q = query@Wq, K = key@Wk, V = value@Wv. Selection is block-uniform:
// blockIdx.x 0..7 -> Q, 8..15 -> K, 16..23 -> V.
__global__ __launch_bounds__(256, 3) void gemm_qkv(
    const unsigned short* __restrict__ Xq, const unsigned short* __restrict__ Xk,
    const unsigned short* __restrict__ Xv, const unsigned short* __restrict__ Wqkv,
    const float* __restrict__ bq, const float* __restrict__ bk,
    const float* __restrict__ bv, unsigned short* __restrict__ Qw,
    unsigned short* __restrict__ Kw, unsigned short* __restrict__ Vt,
    float qscale)
{
    __shared__ unsigned short As[128 * 64];
    __shared__ unsigned short Bs[128 * 64];

    const int tid  = threadIdx.x;
    const int lane = tid & 63, wave = tid >> 6;
    const int l16  = lane & 15, quad = lane >> 4;
    const int wm = wave & 1, wn = wave >> 1;
    const int n0 = blockIdx.x * 128, m0 = blockIdx.y * 128;
    const int xr = l16 & 7;

    const int sel = blockIdx.x >> 3;               // 0=Q, 1=K, 2=V (block-uniform)
    const unsigned short* X = (sel == 0) ? Xq : (sel == 1) ? Xk : Xv;

    const int row8 = lane >> 3;
    const int sc   = ((lane & 7) ^ row8) * 8;

    f32x4 acc[4][4] = {};

    for (int k0 = 0; k0 < D_; k0 += 64) {
        __syncthreads();
        #pragma unroll
        for (int j = 0; j < 4; ++j) {
            const int ca = wave * 4 + j;
            const int r  = ca * 8 + row8;
            gl2lds16(X    + (size_t)(m0 + r) * D_ + k0 + sc, &As[ca * 512 + (lane & 63) * 8]);
            gl2lds16(Wqkv + (size_t)(n0 + r) * D_ + k0 + sc, &Bs[ca * 512 + (lane & 63) * 8]);
        }
        __syncthreads();

        #pragma unroll
        for (int s = 0; s < 2; ++s) {
            bf16x8 a[4], bb[4];
            #pragma unroll
            for (int i = 0; i < 4; ++i)
                a[i] = *(const bf16x8*)&As[(wm * 64 + i * 16 + l16) * 64 + (((s * 4 + quad) ^ xr)) * 8];
            #pragma unroll
            for (int j = 0; j < 4; ++j)
                bb[j] = *(const bf16x8*)&Bs[(wn * 64 + j * 16 + l16) * 64 + (((s * 4 + quad) ^ xr)) * 8];
            #pragma unroll
            for (int i = 0; i < 4; ++i)
                #pragma unroll
                for (int j = 0; j < 4; ++j)
                    acc[i][j] = __builtin_amdgcn_mfma_f32_16x16x32_bf16(a[i], bb[j], acc[i][j], 0, 0, 0);
        }
    }

    const int ncol = (blockIdx.x & 7) * 128 + wn * 64;   // col base within projection
    const float scale = (sel == 0) ? qscale : 1.0f;
    const float* bias = (sel == 0) ? bq : (sel == 1) ? bk : bv;

    if (sel == 2) {
        // V: transposed per-head write Vt[(b*D+dk)*S+s], packed b64 runs along s
        const int bb_ = m0 >> 11;
        #pragma unroll
        for (int j = 0; j < 4; ++j) {
            const int dk = ncol + j * 16 + l16;
            const float bvv = bias[dk];
            #pragma unroll
            for (int i = 0; i < 4; ++i) {
                const int sb = (m0 & (S_ - 1)) + wm * 64 + i * 16 + quad * 4;
                uint2 w;
                w.x = pk_bf16(acc[i][j][0] + bvv, acc[i][j][1] + bvv);
                w.y = pk_bf16(acc[i][j][2] + bvv, acc[i][j][3] + bvv);
                *(uint2*)(Vt + (size_t)(bb_ * D_ + dk) * S_ + sb) = w;
            }
        }
    } else {
        unsigned short* Outp = sel ? Kw : Qw;
        #pragma unroll
        for (int j = 0; j < 4; ++j) {
            const int n = ncol + j * 16 + l16;
            const float bvv = bias[n];
            #pragma unroll
            for (int i = 0; i < 4; ++i) {
                #pragma unroll
                for (int r = 0; r < 4; ++r) {
                    const int m = m0 + wm * 64 + i * 16 + quad * 4 + r;
                    Outp[(size_t)m * D_ + n] = f2bf((acc[i][j][r] + bvv) * scale);
                }
            }
        }
    }
}

// Output GEMM: C = X * W^T + bias (fp32 out), m97 pattern, 128x128 tile.
__global__ __launch_bounds__(256, 3) void gemm_out(
    const unsigned short* __restrict__ X, const unsigned short* __restrict__ W,
    const float* __restrict__ bias, float* __restrict__ Out)
{
    __shared__ unsigned short As[128 * 64];
    __shared__ unsigned short Bs[128 * 64];

    const int tid  = threadIdx.x;
    const int lane = tid & 63, wave = tid >> 6;
    const int l16  = lane & 15, quad = lane >> 4;
    const int wm = wave & 1, wn = wave >> 1;
    const int n0 = blockIdx.x * 128, m0 = blockIdx.y * 128;
    const int xr = l16 & 7;

    const int row8 = lane >> 3;
    const int sc   = ((lane & 7) ^ row8) * 8;

    f32x4 acc[4][4] = {};

    for (int k0 = 0; k0 < D_; k0 += 64) {
        __syncthreads();
        #pragma unroll
        for (int j = 0; j < 4; ++j) {
            const int ca = wave * 4 + j;
            const int r  = ca * 8 + row8;
            gl2lds16(X + (size_t)(m0 + r) * D_ + k0 + sc, &As[ca * 512 + (lane & 63) * 8]);
            gl2lds16(W + (size_t)(n0 + r) * D_ + k0 + sc, &Bs[ca * 512 + (lane & 63) * 8]);
        }
        __syncthreads();

        #pragma unroll
        for (int s = 0; s < 2; ++s) {
            bf16x8 a[4], bb[4];
            #pragma unroll
            for (int i = 0; i < 4; ++i)
                a[i] = *(const bf16x8*)&As[(wm * 64 + i * 16 + l16) * 64 + (((s * 4 + quad) ^ xr)) * 8];
            #pragma unroll
            for (int j = 0; j < 4; ++j)
                bb[j] = *(const bf16x8*)&Bs[(wn * 64 + j * 16 + l16) * 64 + (((s * 4 + quad) ^ xr)) * 8];
            #pragma unroll
            for (int i = 0; i < 4; ++i)
                #pragma unroll
                for (int j = 0; j < 4; ++j)
                    acc[i][j] = __builtin_amdgcn_mfma_f32_16x16x32_bf16(a[i], bb[j], acc[i][j], 0, 0, 0);
        }
    }

    #pragma unroll
    for (int j = 0; j < 4; ++j) {
        const int n = n0 + wn * 64 + j * 16 + l16;
        const float bv = bias[n];
        #pragma unroll
        for (int i = 0; i < 4; ++i) {
            #pragma unroll
            for (int r = 0; r < 4; ++r) {
                const int m = m0 + wm * 64 + i * 16 + quad * 4 + r;
                Out[(size_t)m * D_ + n] = acc[i][j][r] + bv;
            }
        }
    }
}

// Pack mask (B,S,S int32) into bitmask words: pm[(b*S+q)*(S/64)+w] bit k.
__global__ __launch_bounds__(256) void pack_mask(
    const int* __restrict__ mask, unsigned long long* __restrict__ pm)
{
    const int gid  = blockIdx.x * 256 + threadIdx.x;
    const int w    = gid >> 6;
    const int lane = threadIdx.x & 63;
    const int mv = mask[(size_t)w * 64 + lane];
    const unsigned long long bal = __ballot(mv != 0);
    if (lane == 0) pm[w] = bal;
}

// Flash attention, transposed-score, fixed-max softmax, MFMA row-sums.
// R4: Ps LDS round-trip ELIMINATED. QK^T's C-layout puts sct[mb][r] at lane
// (l16,quad) = P[q=l16][k=mb*16+quad*4+r]; the A-fragment of the K=16 MFMA
// (mfma_f32_16x16x16bf16_1k) wants A[row=l16][k=quad*4+j] — the SAME lanes.
// So softmax output feeds PV directly from registers (2 cvt_pk per mb per qf),
// PV runs as 4 K=16 MFMAs per d-block reading V b64 frags from swizzled Vs.
// Removes: Ps (16KB LDS), 8 ds_write + 4 ds_read_b128 per wave-tile, the
// 48-op manual bf16 pack (-> 16 hw cvt_pk), and the softmax->PV LDS
// serialization (VALU of mb i+1 overlaps PV MFMAs of mb i, separate pipes).
// Ks now double-buffered -> ONE barrier per tile. LDS = 2x8K (Ks) + 2x8K (Vs)
// = 32KB. launch_bounds(256,4) -> VGPR cap 128 (est. ~110 live).
__global__ __launch_bounds__(256, 4) void attn_kernel(
    const unsigned short* __restrict__ Q,
    const unsigned short* __restrict__ Kg,
    const unsigned short* __restrict__ Vt,
    const unsigned long long* __restrict__ pm,
    unsigned short* __restrict__ O)
{
    __shared__ unsigned short Ks[2][64 * 64];
    __shared__ unsigned short Vs[2][64 * 64];

    const int tid  = threadIdx.x;
    const int lane = tid & 63, wave = tid >> 6;
    const int l16  = lane & 15, quad = lane >> 4;

    // XCD-chunked swizzle (bijective: 1024 % 8 == 0). gridDim = (16, 64).
    const int n  = blockIdx.y * 16 + blockIdx.x;
    const int ns = (n & 7) * 128 + (n >> 3);
    const int b  = ns >> 8;
    const int h  = (ns >> 4) & 15;
    const int q0 = (ns & 15) * 128;
    const int xq = l16 & 7;

    // all-ones B operand for the row-sum MFMA (K=16 frag: 4 bf16 of 1.0)
    union { uint2 u; short4v v; } ones_u;
    ones_u.u = make_uint2(0x3F803F80u, 0x3F803F80u);
    const short4v vb_ones = ones_u.v;

    // Q fragments: qa[qf][s], wave owns q rows q0 + wave*32 + qf*16 + l16
    bf16x8 qa[2][2];
    #pragma unroll
    for (int qf = 0; qf < 2; ++qf) {
        const unsigned short* qp =
            Q + (size_t)(b * S_ + q0 + wave * 32 + qf * 16 + l16) * D_ + h * DK_ + quad * 8;
        qa[qf][0] = *(const bf16x8*)qp;
        qa[qf][1] = *(const bf16x8*)(qp + 32);
    }

    const unsigned short* Kbase = Kg + (size_t)(b * S_) * D_ + h * DK_;
    const unsigned short* Vbase = Vt + (size_t)(b * D_ + h * DK_) * S_;

    auto stageK = [&](int bi2, int kt2) {
        const int k0 = kt2 * 64;
        #pragma unroll
        for (int j = 0; j < 2; ++j) {
            const int c = j * 256 + tid;
            const int row = c >> 3;
            const int cl = (c & 7) ^ (row & 7);
            gl2lds16(Kbase + (size_t)(k0 + row) * D_ + cl * 8, &Ks[bi2][c * 8]);
        }
    };
    auto stageV = [&](int bi2, int kt2) {
        const int k0 = kt2 * 64;
        #pragma unroll
        for (int j = 0; j < 2; ++j) {
            const int c = j * 256 + tid;
            const int row = c >> 3;
            const int cl = (c & 7) ^ (row & 7);
            gl2lds16(Vbase + (size_t)row * S_ + k0 + cl * 8, &Vs[bi2][c * 8]);
        }
    };

    // PV B-frag LDS element indices (lane-const): V^T[d=db*16+l16][k=mb*16+quad*4..+3]
    // stored swizzled: col-group (k>>3) XOR'd with (row&7); +db*1024 compile-time.
    int vidx[4];
    #pragma unroll
    for (int mb = 0; mb < 4; ++mb)
        vidx[mb] = l16 * 64 + (((mb * 2 + (quad >> 1)) ^ xq) * 8) + (quad & 1) * 4;

    const unsigned long long* pmq0 =
        pm + (size_t)(b * S_ + q0 + wave * 32 + l16) * (S_ / 64);
    const unsigned long long* pmq1 = pmq0 + (size_t)16 * (S_ / 64);

    f32x4 oacc[2][5] = {};

    stageK(0, 0);
    stageV(0, 0);
    __syncthreads();

    int bi = 0;
    for (int kt = 0; kt < S_ / 64; ++kt) {
        const bool more = (kt + 1 < S_ / 64);
        const unsigned long long wq0 = pmq0[kt];
        const unsigned long long wq1 = pmq1[kt];
        if (more) {                      // prefetch next K+V tiles (one barrier/tile)
            stageK(bi ^ 1, kt + 1);
            stageV(bi ^ 1, kt + 1);
        }

        // QK^T both q-frags: S^T rows k (C: row=quad*4+r within mb), cols q (l16)
        f32x4 sct[4][2] = {};
        __builtin_amdgcn_s_setprio(1);
        #pragma unroll
        for (int s = 0; s < 2; ++s) {
            const int cs = ((s * 4 + quad) ^ xq) * 8;
            #pragma unroll
            for (int mb = 0; mb < 4; ++mb) {
                bf16x8 ka = *(const bf16x8*)&Ks[bi][(mb * 16 + l16) * 64 + cs];
                sct[mb][0] = __builtin_amdgcn_mfma_f32_16x16x32_bf16(ka, qa[0][s], sct[mb][0], 0, 0, 0);
                sct[mb][1] = __builtin_amdgcn_mfma_f32_16x16x32_bf16(ka, qa[1][s], sct[mb][1], 0, 0, 0);
            }
        }
        __builtin_amdgcn_s_setprio(0);

        // softmax -> in-register K=16 A-frags (no LDS round-trip)
        short4v a4[2][4];
        #pragma unroll
        for (int qf = 0; qf < 2; ++qf) {
            const unsigned long long wq = qf ? wq1 : wq0;
            #pragma unroll
            for (int mb = 0; mb < 4; ++mb) {
                const unsigned nib = (unsigned)(wq >> (mb * 16 + quad * 4)) & 0xFu;
                float e[4];
                #pragma unroll
                for (int r = 0; r < 4; ++r) {
                    float x = __builtin_amdgcn_exp2f(sct[mb][qf][r]);
                    e[r] = ((nib >> r) & 1u) ? x : 0.f;
                }
                union { uint2 u; short4v v; } pw;
                pw.u.x = cvt_pk_bf16(e[0], e[1]);
                pw.u.y = cvt_pk_bf16(e[2], e[3]);
                a4[qf][mb] = pw.v;
            }
        }

        // PV (+ row-sum via ones frag): 4 K=16 MFMAs span k0..k0+63 per d-block
        __builtin_amdgcn_s_setprio(1);
        #pragma unroll
        for (int mb = 0; mb < 4; ++mb) {
            short4v vb[4];
            #pragma unroll
            for (int db = 0; db < 4; ++db)
                vb[db] = *(const short4v*)&Vs[bi][vidx[mb] + db * 1024];
            #pragma unroll
            for (int db = 0; db < 4; ++db) {
                oacc[0][db] = __builtin_amdgcn_mfma_f32_16x16x16bf16_1k(a4[0][mb], vb[db], oacc[0][db], 0, 0, 0);
                oacc[1][db] = __builtin_amdgcn_mfma_f32_16x16x16bf16_1k(a4[1][mb], vb[db], oacc[1][db], 0, 0, 0);
            }
            oacc[0][4] = __builtin_amdgcn_mfma_f32_16x16x16bf16_1k(a4[0][mb], vb_ones, oacc[0][4], 0, 0, 0);
            oacc[1][4] = __builtin_amdgcn_mfma_f32_16x16x16bf16_1k(a4[1][mb], vb_ones, oacc[1][4], 0, 0, 0);
        }
        __builtin_amdgcn_s_setprio(0);

        __syncthreads();   // drains K+V prefetch (vmcnt0) + guards buffer swap
        bi ^= 1;
    }

    // epilogue: lane holds rows q = quad*4+r, cols d = db*16+l16; sum in oacc[qf][4][r]
    #pragma unroll
    for (int qf = 0; qf < 2; ++qf) {
        #pragma unroll
        for (int r = 0; r < 4; ++r) {
            const float linv = 1.0f / oacc[qf][4][r];
            const int qg = q0 + wave * 32 + qf * 16 + quad * 4 + r;
            #pragma unroll
            for (int db = 0; db < 4; ++db) {
                O[(size_t)(b * S_ + qg) * D_ + h * DK_ + db * 16 + l16] =
                    f2bf(oacc[qf][db][r] * linv);
            }
        }
    }
}

extern "C" void kernel_launch(void* const* d_in, const int* in_sizes, int n_in,
                              void* d_out, int out_size, void* d_ws, size_t ws_size,
                              hipStream_t stream)
{
    const float* q   = (const float*)d_in[0];
    const float* k   = (const float*)d_in[1];
    const float* v   = (const float*)d_in[2];
    const int* mask  = (const int*)d_in[3];
    const float* Wq  = (const float*)d_in[4];
    const float* bq  = (const float*)d_in[5];
    const float* Wk  = (const float*)d_in[6];
    const float* bk  = (const float*)d_in[7];
    const float* Wv  = (const float*)d_in[8];
    const float* bv  = (const float*)d_in[9];
    const float* Wo  = (const float*)d_in[10];
    const float* bo  = (const float*)d_in[11];

    const size_t MN = (size_t)B_ * S_ * D_;    // 8.4M elements
    const size_t WN = (size_t)D_ * D_;         // 1M elements
    unsigned short* qb  = (unsigned short*)d_ws;   // bf16 activations
    unsigned short* kb  = qb + MN;
    unsigned short* vb  = kb + MN;
    unsigned short* Qw  = vb + MN;
    unsigned short* Kw  = Qw + MN;
    unsigned short* Vt  = Kw + MN;
    unsigned short* wqb = Vt + MN;   // weights: wqb/wkb/wvb CONTIGUOUS = Wqkv
    unsigned short* wkb = wqb + WN;
    unsigned short* wvb = wkb + WN;
    unsigned short* wob = wvb + WN;
    unsigned short* Ow  = qb;   // qb dead after QKV-GEMM; attn writes Ow after
    // Packed mask (2 MB) in d_out scratch; final GEMM overwrites all of d_out.
    unsigned long long* pm = (unsigned long long*)d_out;

    dim3 blk(256);
    const int actBlocks = (int)(MN / 8 / 256);   // 4096
    const int wBlocks   = (int)(WN / 8 / 256);   // 512

    pack_mask<<<(B_ * S_ * S_) / 256, blk, 0, stream>>>(mask, pm);

    cast_act<<<dim3(actBlocks, 3), blk, 0, stream>>>(q, k, v, qb, kb, vb);
    cast_w<<<dim3(wBlocks, 4), blk, 0, stream>>>(Wq, Wk, Wv, Wo, wqb, wkb, wvb, wob);

    // Q scaled by log2(e)/sqrt(DK) -> attention scores already in exp2 domain
    const float qscale = 1.44269504088896341f * 0.125f;

    gemm_qkv<<<dim3(3 * D_ / 128, (B_ * S_) / 128), blk, 0, stream>>>(
        qb, kb, vb, wqb, bq, bk, bv, Qw, Kw, Vt, qscale);

    attn_kernel<<<dim3(S_ / 128, B_ * H_), blk, 0, stream>>>(Qw, Kw, Vt, pm, Ow);

    gemm_out<<<dim3(D_ / 128, (B_ * S_) / 128), blk, 0, stream>>>(
        Ow, wob, bo, (float*)d_out);
}

// Round 5
// 398.298 us; speedup vs baseline: 1.0567x; 1.0567x over previous
//
#include <hip/hip_runtime.h>

#define B_  4
#define S_  2048
#define D_  1024
#define H_  16
#define DK_ 64

typedef __attribute__((ext_vector_type(8))) __bf16 bf16x8;
typedef __attribute__((ext_vector_type(4))) float  f32x4;

#define AS1 __attribute__((address_space(1)))
#define AS3 __attribute__((address_space(3)))

// Async 16B global -> LDS. Per-lane dest must equal wave-uniform base + lane*16.
__device__ __forceinline__ void gl2lds16(const void* g, void* l) {
    __builtin_amdgcn_global_load_lds((const AS1 unsigned int*)g,
                                     (AS3 unsigned int*)l, 16, 0, 0);
}

__device__ __forceinline__ unsigned short f2bf(float f) {
    union { float f; unsigned u; } v; v.f = f;
    return (unsigned short)((v.u + 0x7FFFu + ((v.u >> 16) & 1u)) >> 16);
}

// hardware packed f32->bf16 (RNE), 1 VALU op for 2 values (T12 primitive;
// verified correct on this harness in R4 — same absmax as manual rounding)
__device__ __forceinline__ unsigned cvt_pk_bf16(float lo, float hi) {
    unsigned r;
    asm("v_cvt_pk_bf16_f32 %0, %1, %2" : "=v"(r) : "v"(lo), "v"(hi));
    return r;
}

__device__ __forceinline__ void cast8(const float* __restrict__ x,
                                      unsigned short* __restrict__ y, int i) {
    float4 a = ((const float4*)x)[2 * i];
    float4 b = ((const float4*)x)[2 * i + 1];
    uint4 w;
    w.x = cvt_pk_bf16(a.x, a.y);
    w.y = cvt_pk_bf16(a.z, a.w);
    w.z = cvt_pk_bf16(b.x, b.y);
    w.w = cvt_pk_bf16(b.z, b.w);
    ((uint4*)y)[i] = w;
}

// Merged fp32->bf16 casts: grid.y selects tensor (activations q,k,v).
__global__ __launch_bounds__(256) void cast_act(
    const float* __restrict__ a, const float* __restrict__ b,
    const float* __restrict__ c, unsigned short* __restrict__ ya,
    unsigned short* __restrict__ yb, unsigned short* __restrict__ yc)
{
    const int sel = blockIdx.y;
    const float* x = (sel == 0) ? a : (sel == 1) ? b : c;
    unsigned short* y = (sel == 0) ? ya : (sel == 1) ? yb : yc;
    cast8(x, y, blockIdx.x * 256 + threadIdx.x);
}

// Merged weight casts: grid.y in 0..3.
__global__ __launch_bounds__(256) void cast_w(
    const float* __restrict__ a, const float* __restrict__ b,
    const float* __restrict__ c, const float* __restrict__ d,
    unsigned short* __restrict__ ya, unsigned short* __restrict__ yb,
    unsigned short* __restrict__ yc, unsigned short* __restrict__ yd)
{
    const int sel = blockIdx.y;
    const float* x = (sel == 0) ? a : (sel == 1) ? b : (sel == 2) ? c : d;
    unsigned short* y = (sel == 0) ? ya : (sel == 1) ? yb : (sel == 2) ? yc : yd;
    cast8(x, y, blockIdx.x * 256 + threadIdx.x);
}

// Fused QKV projection GEMM over N=3072 output cols (Wq;Wk;Wv rows contiguous).
// CRITICAL (R7/R8 bug): each projection has a DIFFERENT A-operand —
// Q = query@Wq, K = key@Wk, V = value@Wv. Selection is block-uniform.
// R5: XCD-chunked bijective swizzle (1536 blocks, 192/XCD = 8 m-rows x 24 n)
// so each XCD's L2 keeps a compact A/B panel working set instead of the
// scattered round-robin default (T1: A-panels re-read 8x, B-panels 64x).
__global__ __launch_bounds__(256, 3) void gemm_qkv(
    const unsigned short* __restrict__ Xq, const unsigned short* __restrict__ Xk,
    const unsigned short* __restrict__ Xv, const unsigned short* __restrict__ Wqkv,
    const float* __restrict__ bq, const float* __restrict__ bk,
    const float* __restrict__ bv, unsigned short* __restrict__ Qw,
    unsigned short* __restrict__ Kw, unsigned short* __restrict__ Vt,
    float qscale)
{
    __shared__ unsigned short As[128 * 64];
    __shared__ unsigned short Bs[128 * 64];

    const int tid  = threadIdx.x;
    const int lane = tid & 63, wave = tid >> 6;
    const int l16  = lane & 15, quad = lane >> 4;
    const int wm = wave & 1, wn = wave >> 1;

    // XCD swizzle: lin in [0,1536); xcd = lin&7 owns contiguous slin chunk.
    const int lin  = blockIdx.y * 24 + blockIdx.x;
    const int slin = (lin & 7) * 192 + (lin >> 3);
    const int bx = slin % 24, by = slin / 24;

    const int n0 = bx * 128, m0 = by * 128;
    const int xr = l16 & 7;

    const int sel = bx >> 3;               // 0=Q, 1=K, 2=V (block-uniform)
    const unsigned short* X = (sel == 0) ? Xq : (sel == 1) ? Xk : Xv;

    const int row8 = lane >> 3;
    const int sc   = ((lane & 7) ^ row8) * 8;

    f32x4 acc[4][4] = {};

    for (int k0 = 0; k0 < D_; k0 += 64) {
        __syncthreads();
        #pragma unroll
        for (int j = 0; j < 4; ++j) {
            const int ca = wave * 4 + j;
            const int r  = ca * 8 + row8;
            gl2lds16(X    + (size_t)(m0 + r) * D_ + k0 + sc, &As[ca * 512 + (lane & 63) * 8]);
            gl2lds16(Wqkv + (size_t)(n0 + r) * D_ + k0 + sc, &Bs[ca * 512 + (lane & 63) * 8]);
        }
        __syncthreads();

        #pragma unroll
        for (int s = 0; s < 2; ++s) {
            bf16x8 a[4], bb[4];
            #pragma unroll
            for (int i = 0; i < 4; ++i)
                a[i] = *(const bf16x8*)&As[(wm * 64 + i * 16 + l16) * 64 + (((s * 4 + quad) ^ xr)) * 8];
            #pragma unroll
            for (int j = 0; j < 4; ++j)
                bb[j] = *(const bf16x8*)&Bs[(wn * 64 + j * 16 + l16) * 64 + (((s * 4 + quad) ^ xr)) * 8];
            #pragma unroll
            for (int i = 0; i < 4; ++i)
                #pragma unroll
                for (int j = 0; j < 4; ++j)
                    acc[i][j] = __builtin_amdgcn_mfma_f32_16x16x32_bf16(a[i], bb[j], acc[i][j], 0, 0, 0);
        }
    }

    const int ncol = (bx & 7) * 128 + wn * 64;   // col base within projection
    const float scale = (sel == 0) ? qscale : 1.0f;
    const float* bias = (sel == 0) ? bq : (sel == 1) ? bk : bv;

    if (sel == 2) {
        // V: transposed per-head write Vt[(b*D+dk)*S+s], packed b64 runs along s
        const int bb_ = m0 >> 11;
        #pragma unroll
        for (int j = 0; j < 4; ++j) {
            const int dk = ncol + j * 16 + l16;
            const float bvv = bias[dk];
            #pragma unroll
            for (int i = 0; i < 4; ++i) {
                const int sb = (m0 & (S_ - 1)) + wm * 64 + i * 16 + quad * 4;
                uint2 w;
                w.x = cvt_pk_bf16(acc[i][j][0] + bvv, acc[i][j][1] + bvv);
                w.y = cvt_pk_bf16(acc[i][j][2] + bvv, acc[i][j][3] + bvv);
                *(uint2*)(Vt + (size_t)(bb_ * D_ + dk) * S_ + sb) = w;
            }
        }
    } else {
        unsigned short* Outp = sel ? Kw : Qw;
        #pragma unroll
        for (int j = 0; j < 4; ++j) {
            const int n = ncol + j * 16 + l16;
            const float bvv = bias[n];
            #pragma unroll
            for (int i = 0; i < 4; ++i) {
                #pragma unroll
                for (int r = 0; r < 4; ++r) {
                    const int m = m0 + wm * 64 + i * 16 + quad * 4 + r;
                    Outp[(size_t)m * D_ + n] = f2bf((acc[i][j][r] + bvv) * scale);
                }
            }
        }
    }
}

// Output GEMM: C = X * W^T + bias (fp32 out), m97 pattern, 128x128 tile.
// R5: XCD swizzle (512 blocks, 64/XCD = 8m x 8n -> 4MB working set = one L2).
__global__ __launch_bounds__(256, 3) void gemm_out(
    const unsigned short* __restrict__ X, const unsigned short* __restrict__ W,
    const float* __restrict__ bias, float* __restrict__ Out)
{
    __shared__ unsigned short As[128 * 64];
    __shared__ unsigned short Bs[128 * 64];

    const int tid  = threadIdx.x;
    const int lane = tid & 63, wave = tid >> 6;
    const int l16  = lane & 15, quad = lane >> 4;
    const int wm = wave & 1, wn = wave >> 1;

    const int lin  = blockIdx.y * 8 + blockIdx.x;
    const int slin = (lin & 7) * 64 + (lin >> 3);
    const int bx = slin & 7, by = slin >> 3;

    const int n0 = bx * 128, m0 = by * 128;
    const int xr = l16 & 7;

    const int row8 = lane >> 3;
    const int sc   = ((lane & 7) ^ row8) * 8;

    f32x4 acc[4][4] = {};

    for (int k0 = 0; k0 < D_; k0 += 64) {
        __syncthreads();
        #pragma unroll
        for (int j = 0; j < 4; ++j) {
            const int ca = wave * 4 + j;
            const int r  = ca * 8 + row8;
            gl2lds16(X + (size_t)(m0 + r) * D_ + k0 + sc, &As[ca * 512 + (lane & 63) * 8]);
            gl2lds16(W + (size_t)(n0 + r) * D_ + k0 + sc, &Bs[ca * 512 + (lane & 63) * 8]);
        }
        __syncthreads();

        #pragma unroll
        for (int s = 0; s < 2; ++s) {
            bf16x8 a[4], bb[4];
            #pragma unroll
            for (int i = 0; i < 4; ++i)
                a[i] = *(const bf16x8*)&As[(wm * 64 + i * 16 + l16) * 64 + (((s * 4 + quad) ^ xr)) * 8];
            #pragma unroll
            for (int j = 0; j < 4; ++j)
                bb[j] = *(const bf16x8*)&Bs[(wn * 64 + j * 16 + l16) * 64 + (((s * 4 + quad) ^ xr)) * 8];
            #pragma unroll
            for (int i = 0; i < 4; ++i)
                #pragma unroll
                for (int j = 0; j < 4; ++j)
                    acc[i][j] = __builtin_amdgcn_mfma_f32_16x16x32_bf16(a[i], bb[j], acc[i][j], 0, 0, 0);
        }
    }

    #pragma unroll
    for (int j = 0; j < 4; ++j) {
        const int n = n0 + wn * 64 + j * 16 + l16;
        const float bv = bias[n];
        #pragma unroll
        for (int i = 0; i < 4; ++i) {
            #pragma unroll
            for (int r = 0; r < 4; ++r) {
                const int m = m0 + wm * 64 + i * 16 + quad * 4 + r;
                Out[(size_t)m * D_ + n] = acc[i][j][r] + bv;
            }
        }
    }
}

// Pack mask (B,S,S int32) into bitmask words: pm[(b*S+q)*(S/64)+w] bit k.
__global__ __launch_bounds__(256) void pack_mask(
    const int* __restrict__ mask, unsigned long long* __restrict__ pm)
{
    const int gid  = blockIdx.x * 256 + threadIdx.x;
    const int w    = gid >> 6;
    const int lane = threadIdx.x & 63;
    const int mv = mask[(size_t)w * 64 + lane];
    const unsigned long long bal = __ballot(mv != 0);
    if (lane == 0) pm[w] = bal;
}

// Flash attention, transposed-score, fixed-max softmax, MFMA row-sums.
// R5 = R3 structure (best measured: 110.3 us) with ONE change: softmax
// bf16 pack uses hw v_cvt_pk_bf16_f32 (1 op) instead of manual pk_bf16
// (3 ops) — R3's VALU was the binding pipe (58.7% busy), pack was ~25%
// of softmax VALU. R4's K=16 register-PV is reverted (MFMA issue count
// doubled and bank conflicts doubled; net +3.4 us).
// QBLK=128 (wave owns 32 q rows), KVBLK=64; LDS 40KB = Ks 8K (single-buf,
// staged under PV after mid barrier) + Vs 2x8K (dbuf) + Ps 16K -> 4
// blocks/CU, grid 1024 = exactly one fully-resident round.
__global__ __launch_bounds__(256, 4) void attn_kernel(
    const unsigned short* __restrict__ Q,
    const unsigned short* __restrict__ Kg,
    const unsigned short* __restrict__ Vt,
    const unsigned long long* __restrict__ pm,
    unsigned short* __restrict__ O)
{
    __shared__ unsigned short Ks[64 * 64];
    __shared__ unsigned short Vs[2][64 * 64];
    __shared__ unsigned short Ps[128 * 64];

    const int tid  = threadIdx.x;
    const int lane = tid & 63, wave = tid >> 6;
    const int l16  = lane & 15, quad = lane >> 4;

    // XCD-chunked swizzle (bijective: 1024 % 8 == 0). gridDim = (16, 64).
    const int n  = blockIdx.y * 16 + blockIdx.x;
    const int ns = (n & 7) * 128 + (n >> 3);
    const int b  = ns >> 8;
    const int h  = (ns >> 4) & 15;
    const int q0 = (ns & 15) * 128;
    const int xq = l16 & 7;

    // all-ones B operand for the row-sum MFMA
    union { uint4 u; bf16x8 v; } ones_u;
    ones_u.u = make_uint4(0x3F803F80u, 0x3F803F80u, 0x3F803F80u, 0x3F803F80u);
    const bf16x8 vb_ones = ones_u.v;

    // Q fragments: qa[qf][s], wave owns q rows q0 + wave*32 + qf*16 + l16
    bf16x8 qa[2][2];
    #pragma unroll
    for (int qf = 0; qf < 2; ++qf) {
        const unsigned short* qp =
            Q + (size_t)(b * S_ + q0 + wave * 32 + qf * 16 + l16) * D_ + h * DK_ + quad * 8;
        qa[qf][0] = *(const bf16x8*)qp;
        qa[qf][1] = *(const bf16x8*)(qp + 32);
    }

    const unsigned short* Kbase = Kg + (size_t)(b * S_) * D_ + h * DK_;
    const unsigned short* Vbase = Vt + (size_t)(b * D_ + h * DK_) * S_;

    auto stageK = [&](int kt2) {
        const int k0 = kt2 * 64;
        #pragma unroll
        for (int j = 0; j < 2; ++j) {
            const int c = j * 256 + tid;
            const int row = c >> 3;
            const int cl = (c & 7) ^ (row & 7);
            gl2lds16(Kbase + (size_t)(k0 + row) * D_ + cl * 8, &Ks[c * 8]);
        }
    };
    auto stageV = [&](int bi2, int kt2) {
        const int k0 = kt2 * 64;
        #pragma unroll
        for (int j = 0; j < 2; ++j) {
            const int c = j * 256 + tid;
            const int row = c >> 3;
            const int cl = (c & 7) ^ (row & 7);
            gl2lds16(Vbase + (size_t)row * S_ + k0 + cl * 8, &Vs[bi2][c * 8]);
        }
    };

    const unsigned long long* pmq0 =
        pm + (size_t)(b * S_ + q0 + wave * 32 + l16) * (S_ / 64);
    const unsigned long long* pmq1 = pmq0 + (size_t)16 * (S_ / 64);

    f32x4 oacc[2][5] = {};

    stageK(0);
    stageV(0, 0);
    __syncthreads();

    int bi = 0;
    for (int kt = 0; kt < S_ / 64; ++kt) {
        const bool more = (kt + 1 < S_ / 64);
        const unsigned long long wq0 = pmq0[kt];
        const unsigned long long wq1 = pmq1[kt];
        if (more) stageV(bi ^ 1, kt + 1);   // V prefetch overlaps QK^T + softmax

        // QK^T + softmax in two mb-halves (keeps sct at 16 regs).
        #pragma unroll
        for (int half = 0; half < 2; ++half) {
            f32x4 sct[2][2] = {};
            __builtin_amdgcn_s_setprio(1);
            #pragma unroll
            for (int s = 0; s < 2; ++s) {
                const int cs = ((s * 4 + quad) ^ xq) * 8;
                #pragma unroll
                for (int mbh = 0; mbh < 2; ++mbh) {
                    bf16x8 ka = *(const bf16x8*)&Ks[((half * 2 + mbh) * 16 + l16) * 64 + cs];
                    sct[mbh][0] = __builtin_amdgcn_mfma_f32_16x16x32_bf16(ka, qa[0][s], sct[mbh][0], 0, 0, 0);
                    sct[mbh][1] = __builtin_amdgcn_mfma_f32_16x16x32_bf16(ka, qa[1][s], sct[mbh][1], 0, 0, 0);
                }
            }
            __builtin_amdgcn_s_setprio(0);

            #pragma unroll
            for (int qf = 0; qf < 2; ++qf) {
                const unsigned long long wq = qf ? wq1 : wq0;
                #pragma unroll
                for (int mbh = 0; mbh < 2; ++mbh) {
                    const int mb = half * 2 + mbh;
                    const unsigned nib = (unsigned)(wq >> (mb * 16 + quad * 4)) & 0xFu;
                    float e[4];
                    #pragma unroll
                    for (int r = 0; r < 4; ++r) {
                        float x = __builtin_amdgcn_exp2f(sct[mbh][qf][r]);
                        e[r] = ((nib >> r) & 1u) ? x : 0.f;
                    }
                    uint2 w;
                    w.x = cvt_pk_bf16(e[0], e[1]);
                    w.y = cvt_pk_bf16(e[2], e[3]);
                    *(uint2*)&Ps[(wave * 32 + qf * 16 + l16) * 64 +
                                 ((mb * 16 + quad * 4) ^ (xq * 8))] = w;
                }
            }
        }

        __syncthreads();                 // all waves done reading Ks
        if (more) stageK(kt + 1);        // K staging overlaps PV

        // PV (+ row-sum via constant ones B): A = P rows (q), B = Vs rows (d)
        __builtin_amdgcn_s_setprio(1);
        #pragma unroll
        for (int s = 0; s < 2; ++s) {
            const int cs = ((s * 4 + quad) ^ xq) * 8;
            bf16x8 pa0 = *(const bf16x8*)&Ps[(wave * 32 + l16) * 64 +
                                             ((s * 32 + quad * 8) ^ (xq * 8))];
            bf16x8 pa1 = *(const bf16x8*)&Ps[(wave * 32 + 16 + l16) * 64 +
                                             ((s * 32 + quad * 8) ^ (xq * 8))];
            #pragma unroll
            for (int db = 0; db < 4; ++db) {
                bf16x8 vb = *(const bf16x8*)&Vs[bi][(db * 16 + l16) * 64 + cs];
                oacc[0][db] = __builtin_amdgcn_mfma_f32_16x16x32_bf16(pa0, vb, oacc[0][db], 0, 0, 0);
                oacc[1][db] = __builtin_amdgcn_mfma_f32_16x16x32_bf16(pa1, vb, oacc[1][db], 0, 0, 0);
            }
            oacc[0][4] = __builtin_amdgcn_mfma_f32_16x16x32_bf16(pa0, vb_ones, oacc[0][4], 0, 0, 0);
            oacc[1][4] = __builtin_amdgcn_mfma_f32_16x16x32_bf16(pa1, vb_ones, oacc[1][4], 0, 0, 0);
        }
        __builtin_amdgcn_s_setprio(0);

        __syncthreads();   // drains K+V staging (vmcnt0) + guards Vs swap
        bi ^= 1;
    }

    // epilogue: lane holds rows q = quad*4+r, cols d = db*16+l16; sum in oacc[qf][4][r]
    #pragma unroll
    for (int qf = 0; qf < 2; ++qf) {
        #pragma unroll
        for (int r = 0; r < 4; ++r) {
            const float linv = 1.0f / oacc[qf][4][r];
            const int qg = q0 + wave * 32 + qf * 16 + quad * 4 + r;
            #pragma unroll
            for (int db = 0; db < 4; ++db) {
                O[(size_t)(b * S_ + qg) * D_ + h * DK_ + db * 16 + l16] =
                    f2bf(oacc[qf][db][r] * linv);
            }
        }
    }
}

extern "C" void kernel_launch(void* const* d_in, const int* in_sizes, int n_in,
                              void* d_out, int out_size, void* d_ws, size_t ws_size,
                              hipStream_t stream)
{
    const float* q   = (const float*)d_in[0];
    const float* k   = (const float*)d_in[1];
    const float* v   = (const float*)d_in[2];
    const int* mask  = (const int*)d_in[3];
    const float* Wq  = (const float*)d_in[4];
    const float* bq  = (const float*)d_in[5];
    const float* Wk  = (const float*)d_in[6];
    const float* bk  = (const float*)d_in[7];
    const float* Wv  = (const float*)d_in[8];
    const float* bv  = (const float*)d_in[9];
    const float* Wo  = (const float*)d_in[10];
    const float* bo  = (const float*)d_in[11];

    const size_t MN = (size_t)B_ * S_ * D_;    // 8.4M elements
    const size_t WN = (size_t)D_ * D_;         // 1M elements
    unsigned short* qb  = (unsigned short*)d_ws;   // bf16 activations
    unsigned short* kb  = qb + MN;
    unsigned short* vb  = kb + MN;
    unsigned short* Qw  = vb + MN;
    unsigned short* Kw  = Qw + MN;
    unsigned short* Vt  = Kw + MN;
    unsigned short* wqb = Vt + MN;   // weights: wqb/wkb/wvb CONTIGUOUS = Wqkv
    unsigned short* wkb = wqb + WN;
    unsigned short* wvb = wkb + WN;
    unsigned short* wob = wvb + WN;
    unsigned short* Ow  = qb;   // qb dead after QKV-GEMM; attn writes Ow after
    // Packed mask (2 MB) in d_out scratch; final GEMM overwrites all of d_out.
    unsigned long long* pm = (unsigned long long*)d_out;

    dim3 blk(256);
    const int actBlocks = (int)(MN / 8 / 256);   // 4096
    const int wBlocks   = (int)(WN / 8 / 256);   // 512

    pack_mask<<<(B_ * S_ * S_) / 256, blk, 0, stream>>>(mask, pm);

    cast_act<<<dim3(actBlocks, 3), blk, 0, stream>>>(q, k, v, qb, kb, vb);
    cast_w<<<dim3(wBlocks, 4), blk, 0, stream>>>(Wq, Wk, Wv, Wo, wqb, wkb, wvb, wob);

    // Q scaled by log2(e)/sqrt(DK) -> attention scores already in exp2 domain
    const float qscale = 1.44269504088896341f * 0.125f;

    gemm_qkv<<<dim3(3 * D_ / 128, (B_ * S_) / 128), blk, 0, stream>>>(
        qb, kb, vb, wqb, bq, bk, bv, Qw, Kw, Vt, qscale);

    attn_kernel<<<dim3(S_ / 128, B_ * H_), blk, 0, stream>>>(Qw, Kw, Vt, pm, Ow);

    gemm_out<<<dim3(D_ / 128, (B_ * S_) / 128), blk, 0, stream>>>(
        Ow, wob, bo, (float*)d_out);
}

// Round 7
// 395.731 us; speedup vs baseline: 1.0635x; 1.0065x over previous
//
#include <hip/hip_runtime.h>

#define B_  4
#define S_  2048
#define D_  1024
#define H_  16
#define DK_ 64

typedef __attribute__((ext_vector_type(8))) __bf16 bf16x8;
typedef __attribute__((ext_vector_type(4))) float  f32x4;

#define AS1 __attribute__((address_space(1)))
#define AS3 __attribute__((address_space(3)))

// Async 16B global -> LDS. Per-lane dest must equal wave-uniform base + lane*16.
__device__ __forceinline__ void gl2lds16(const void* g, void* l) {
    __builtin_amdgcn_global_load_lds((const AS1 unsigned int*)g,
                                     (AS3 unsigned int*)l, 16, 0, 0);
}

__device__ __forceinline__ unsigned short f2bf(float f) {
    union { float f; unsigned u; } v; v.f = f;
    return (unsigned short)((v.u + 0x7FFFu + ((v.u >> 16) & 1u)) >> 16);
}

// hardware packed f32->bf16 (RNE), 1 VALU op for 2 values (T12 primitive;
// verified correct on this harness since R4 — same absmax as manual rounding)
__device__ __forceinline__ unsigned cvt_pk_bf16(float lo, float hi) {
    unsigned r;
    asm("v_cvt_pk_bf16_f32 %0, %1, %2" : "=v"(r) : "v"(lo), "v"(hi));
    return r;
}

__device__ __forceinline__ void cast8(const float* __restrict__ x,
                                      unsigned short* __restrict__ y, int i) {
    float4 a = ((const float4*)x)[2 * i];
    float4 b = ((const float4*)x)[2 * i + 1];
    uint4 w;
    w.x = cvt_pk_bf16(a.x, a.y);
    w.y = cvt_pk_bf16(a.z, a.w);
    w.z = cvt_pk_bf16(b.x, b.y);
    w.w = cvt_pk_bf16(b.z, b.w);
    ((uint4*)y)[i] = w;
}

// R6 (resubmit; prior run died to container infra, not the kernel):
// ALL preprocessing in ONE launch (was cast_act + cast_w + pack_mask =
// 3 launches): saves 2 inter-kernel gaps; pack_mask grid-strided (65536 ->
// 2048 WGs — per-WG work was one wave-instr, dispatch overhead suspect).
// Branches are block-uniform. grid = 12288 (act) + 2048 (w) + 2048 (mask).
__global__ __launch_bounds__(256) void prep_all(
    const float* __restrict__ q, const float* __restrict__ k,
    const float* __restrict__ v, const float* __restrict__ Wq,
    const float* __restrict__ Wk, const float* __restrict__ Wv,
    const float* __restrict__ Wo, const int* __restrict__ mask,
    unsigned short* __restrict__ qb, unsigned short* __restrict__ kb,
    unsigned short* __restrict__ vb, unsigned short* __restrict__ wqb,
    unsigned short* __restrict__ wkb, unsigned short* __restrict__ wvb,
    unsigned short* __restrict__ wob, unsigned long long* __restrict__ pmo)
{
    const int bid = blockIdx.x;
    if (bid < 12288) {                         // activations: 3 x 4096 blocks
        const int sel = bid >> 12;
        const float* x = (sel == 0) ? q : (sel == 1) ? k : v;
        unsigned short* y = (sel == 0) ? qb : (sel == 1) ? kb : vb;
        cast8(x, y, (bid & 4095) * 256 + threadIdx.x);
    } else if (bid < 14336) {                  // weights: 4 x 512 blocks
        const int b2 = bid - 12288;
        const int sel = b2 >> 9;
        const float* x = (sel == 0) ? Wq : (sel == 1) ? Wk : (sel == 2) ? Wv : Wo;
        unsigned short* y = (sel == 0) ? wqb : (sel == 1) ? wkb : (sel == 2) ? wvb : wob;
        cast8(x, y, (b2 & 511) * 256 + threadIdx.x);
    } else {                                   // mask pack: 2048 blocks, strided
        const int b3 = bid - 14336;
        const int lane = threadIdx.x & 63;
        int w = (b3 * 256 + (int)threadIdx.x) >> 6;     // [0, 8192)
        #pragma unroll 4
        for (int it = 0; it < 32; ++it, w += 8192) {    // 262144 words total
            const int mv = mask[(size_t)w * 64 + lane];
            const unsigned long long bal = __ballot(mv != 0);
            if (lane == 0) pmo[w] = bal;
        }
    }
}

// Fused QKV projection GEMM over N=3072 output cols (Wq;Wk;Wv rows contiguous).
// CRITICAL (R7/R8 bug): each projection has a DIFFERENT A-operand —
// Q = query@Wq, K = key@Wk, V = value@Wv. Selection is block-uniform.
// R6: within-XCD 2D grouping (4 n-cols x 8 m-rows per group). Old order
// swept all 24 n per m-row -> 6MB Wqkv panel > 4MB L2 -> W thrash from L3.
// New resident set per group = W 1MB + A-panel 256KB << L2, W fetched once.
__global__ __launch_bounds__(256, 3) void gemm_qkv(
    const unsigned short* __restrict__ Xq, const unsigned short* __restrict__ Xk,
    const unsigned short* __restrict__ Xv, const unsigned short* __restrict__ Wqkv,
    const float* __restrict__ bq, const float* __restrict__ bk,
    const float* __restrict__ bv, unsigned short* __restrict__ Qw,
    unsigned short* __restrict__ Kw, unsigned short* __restrict__ Vt,
    float qscale)
{
    __shared__ unsigned short As[128 * 64];
    __shared__ unsigned short Bs[128 * 64];

    const int tid  = threadIdx.x;
    const int lane = tid & 63, wave = tid >> 6;
    const int l16  = lane & 15, quad = lane >> 4;
    const int wm = wave & 1, wn = wave >> 1;

    // XCD swizzle + 2D grouping: lin in [0,1536); xcd = lin&7; i in [0,192);
    // group ng (6 of 4 n-cols), within group 8 m-rows x 4 n-cols.
    const int lin = blockIdx.y * 24 + blockIdx.x;
    const int xcd = lin & 7;
    const int i   = lin >> 3;
    const int ng  = i >> 5;
    const int r_  = i & 31;
    const int bx  = ng * 4 + (r_ & 3);        // [0,24)
    const int by  = xcd * 8 + (r_ >> 2);      // [0,64)

    const int n0 = bx * 128, m0 = by * 128;
    const int xr = l16 & 7;

    const int sel = bx >> 3;               // 0=Q, 1=K, 2=V (block-uniform)
    const unsigned short* X = (sel == 0) ? Xq : (sel == 1) ? Xk : Xv;

    const int row8 = lane >> 3;
    const int sc   = ((lane & 7) ^ row8) * 8;

    f32x4 acc[4][4] = {};

    for (int k0 = 0; k0 < D_; k0 += 64) {
        __syncthreads();
        #pragma unroll
        for (int j = 0; j < 4; ++j) {
            const int ca = wave * 4 + j;
            const int r  = ca * 8 + row8;
            gl2lds16(X    + (size_t)(m0 + r) * D_ + k0 + sc, &As[ca * 512 + (lane & 63) * 8]);
            gl2lds16(Wqkv + (size_t)(n0 + r) * D_ + k0 + sc, &Bs[ca * 512 + (lane & 63) * 8]);
        }
        __syncthreads();

        #pragma unroll
        for (int s = 0; s < 2; ++s) {
            bf16x8 a[4], bb[4];
            #pragma unroll
            for (int i2 = 0; i2 < 4; ++i2)
                a[i2] = *(const bf16x8*)&As[(wm * 64 + i2 * 16 + l16) * 64 + (((s * 4 + quad) ^ xr)) * 8];
            #pragma unroll
            for (int j = 0; j < 4; ++j)
                bb[j] = *(const bf16x8*)&Bs[(wn * 64 + j * 16 + l16) * 64 + (((s * 4 + quad) ^ xr)) * 8];
            #pragma unroll
            for (int i2 = 0; i2 < 4; ++i2)
                #pragma unroll
                for (int j = 0; j < 4; ++j)
                    acc[i2][j] = __builtin_amdgcn_mfma_f32_16x16x32_bf16(a[i2], bb[j], acc[i2][j], 0, 0, 0);
        }
    }

    const int ncol = (bx & 7) * 128 + wn * 64;   // col base within projection
    const float scale = (sel == 0) ? qscale : 1.0f;
    const float* bias = (sel == 0) ? bq : (sel == 1) ? bk : bv;

    if (sel == 2) {
        // V: transposed per-head write Vt[(b*D+dk)*S+s], packed b64 runs along s
        const int bb_ = m0 >> 11;
        #pragma unroll
        for (int j = 0; j < 4; ++j) {
            const int dk = ncol + j * 16 + l16;
            const float bvv = bias[dk];
            #pragma unroll
            for (int i2 = 0; i2 < 4; ++i2) {
                const int sb = (m0 & (S_ - 1)) + wm * 64 + i2 * 16 + quad * 4;
                uint2 w;
                w.x = cvt_pk_bf16(acc[i2][j][0] + bvv, acc[i2][j][1] + bvv);
                w.y = cvt_pk_bf16(acc[i2][j][2] + bvv, acc[i2][j][3] + bvv);
                *(uint2*)(Vt + (size_t)(bb_ * D_ + dk) * S_ + sb) = w;
            }
        }
    } else {
        unsigned short* Outp = sel ? Kw : Qw;
        #pragma unroll
        for (int j = 0; j < 4; ++j) {
            const int n = ncol + j * 16 + l16;
            const float bvv = bias[n];
            #pragma unroll
            for (int i2 = 0; i2 < 4; ++i2) {
                #pragma unroll
                for (int r = 0; r < 4; ++r) {
                    const int m = m0 + wm * 64 + i2 * 16 + quad * 4 + r;
                    Outp[(size_t)m * D_ + n] = f2bf((acc[i2][j][r] + bvv) * scale);
                }
            }
        }
    }
}

// Output GEMM: C = X * W^T + bias (fp32 out), m97 pattern, 128x128 tile.
// R6: within-XCD 2D grouping (4n x 8m): W-group 1MB + A-panel 256KB in L2.
__global__ __launch_bounds__(256, 3) void gemm_out(
    const unsigned short* __restrict__ X, const unsigned short* __restrict__ W,
    const float* __restrict__ bias, float* __restrict__ Out)
{
    __shared__ unsigned short As[128 * 64];
    __shared__ unsigned short Bs[128 * 64];

    const int tid  = threadIdx.x;
    const int lane = tid & 63, wave = tid >> 6;
    const int l16  = lane & 15, quad = lane >> 4;
    const int wm = wave & 1, wn = wave >> 1;

    const int lin = blockIdx.y * 8 + blockIdx.x;  // [0,512)
    const int xcd = lin & 7;
    const int i   = lin >> 3;                     // [0,64)
    const int ng  = i >> 5;                       // {0,1}
    const int r_  = i & 31;
    const int bx  = ng * 4 + (r_ & 3);            // [0,8)
    const int by  = xcd * 8 + (r_ >> 2);          // [0,64)

    const int n0 = bx * 128, m0 = by * 128;
    const int xr = l16 & 7;

    const int row8 = lane >> 3;
    const int sc   = ((lane & 7) ^ row8) * 8;

    f32x4 acc[4][4] = {};

    for (int k0 = 0; k0 < D_; k0 += 64) {
        __syncthreads();
        #pragma unroll
        for (int j = 0; j < 4; ++j) {
            const int ca = wave * 4 + j;
            const int r  = ca * 8 + row8;
            gl2lds16(X + (size_t)(m0 + r) * D_ + k0 + sc, &As[ca * 512 + (lane & 63) * 8]);
            gl2lds16(W + (size_t)(n0 + r) * D_ + k0 + sc, &Bs[ca * 512 + (lane & 63) * 8]);
        }
        __syncthreads();

        #pragma unroll
        for (int s = 0; s < 2; ++s) {
            bf16x8 a[4], bb[4];
            #pragma unroll
            for (int i2 = 0; i2 < 4; ++i2)
                a[i2] = *(const bf16x8*)&As[(wm * 64 + i2 * 16 + l16) * 64 + (((s * 4 + quad) ^ xr)) * 8];
            #pragma unroll
            for (int j = 0; j < 4; ++j)
                bb[j] = *(const bf16x8*)&Bs[(wn * 64 + j * 16 + l16) * 64 + (((s * 4 + quad) ^ xr)) * 8];
            #pragma unroll
            for (int i2 = 0; i2 < 4; ++i2)
                #pragma unroll
                for (int j = 0; j < 4; ++j)
                    acc[i2][j] = __builtin_amdgcn_mfma_f32_16x16x32_bf16(a[i2], bb[j], acc[i2][j], 0, 0, 0);
        }
    }

    #pragma unroll
    for (int j = 0; j < 4; ++j) {
        const int n = n0 + wn * 64 + j * 16 + l16;
        const float bv = bias[n];
        #pragma unroll
        for (int i2 = 0; i2 < 4; ++i2) {
            #pragma unroll
            for (int r = 0; r < 4; ++r) {
                const int m = m0 + wm * 64 + i2 * 16 + quad * 4 + r;
                Out[(size_t)m * D_ + n] = acc[i2][j][r] + bv;
            }
        }
    }
}

// Flash attention, transposed-score, fixed-max softmax, MFMA row-sums.
// R5 structure (best measured: 104.3 us), unchanged. At structural
// plateau: LDS pipe ~65% (K+V bytes irreducible per tiling), VALU 54%,
// MFMA 31%, occupancy pinned at 16 waves/CU by rows-per-wave tradeoff.
// QBLK=128 (wave owns 32 q rows), KVBLK=64; LDS 40KB = Ks 8K (single-buf,
// staged under PV after mid barrier) + Vs 2x8K (dbuf) + Ps 16K -> 4
// blocks/CU, grid 1024 = exactly one fully-resident round.
__global__ __launch_bounds__(256, 4) void attn_kernel(
    const unsigned short* __restrict__ Q,
    const unsigned short* __restrict__ Kg,
    const unsigned short* __restrict__ Vt,
    const unsigned long long* __restrict__ pm,
    unsigned short* __restrict__ O)
{
    __shared__ unsigned short Ks[64 * 64];
    __shared__ unsigned short Vs[2][64 * 64];
    __shared__ unsigned short Ps[128 * 64];

    const int tid  = threadIdx.x;
    const int lane = tid & 63, wave = tid >> 6;
    const int l16  = lane & 15, quad = lane >> 4;

    // XCD-chunked swizzle (bijective: 1024 % 8 == 0). gridDim = (16, 64).
    const int n  = blockIdx.y * 16 + blockIdx.x;
    const int ns = (n & 7) * 128 + (n >> 3);
    const int b  = ns >> 8;
    const int h  = (ns >> 4) & 15;
    const int q0 = (ns & 15) * 128;
    const int xq = l16 & 7;

    // all-ones B operand for the row-sum MFMA
    union { uint4 u; bf16x8 v; } ones_u;
    ones_u.u = make_uint4(0x3F803F80u, 0x3F803F80u, 0x3F803F80u, 0x3F803F80u);
    const bf16x8 vb_ones = ones_u.v;

    // Q fragments: qa[qf][s], wave owns q rows q0 + wave*32 + qf*16 + l16
    bf16x8 qa[2][2];
    #pragma unroll
    for (int qf = 0; qf < 2; ++qf) {
        const unsigned short* qp =
            Q + (size_t)(b * S_ + q0 + wave * 32 + qf * 16 + l16) * D_ + h * DK_ + quad * 8;
        qa[qf][0] = *(const bf16x8*)qp;
        qa[qf][1] = *(const bf16x8*)(qp + 32);
    }

    const unsigned short* Kbase = Kg + (size_t)(b * S_) * D_ + h * DK_;
    const unsigned short* Vbase = Vt + (size_t)(b * D_ + h * DK_) * S_;

    auto stageK = [&](int kt2) {
        const int k0 = kt2 * 64;
        #pragma unroll
        for (int j = 0; j < 2; ++j) {
            const int c = j * 256 + tid;
            const int row = c >> 3;
            const int cl = (c & 7) ^ (row & 7);
            gl2lds16(Kbase + (size_t)(k0 + row) * D_ + cl * 8, &Ks[c * 8]);
        }
    };
    auto stageV = [&](int bi2, int kt2) {
        const int k0 = kt2 * 64;
        #pragma unroll
        for (int j = 0; j < 2; ++j) {
            const int c = j * 256 + tid;
            const int row = c >> 3;
            const int cl = (c & 7) ^ (row & 7);
            gl2lds16(Vbase + (size_t)row * S_ + k0 + cl * 8, &Vs[bi2][c * 8]);
        }
    };

    const unsigned long long* pmq0 =
        pm + (size_t)(b * S_ + q0 + wave * 32 + l16) * (S_ / 64);
    const unsigned long long* pmq1 = pmq0 + (size_t)16 * (S_ / 64);

    f32x4 oacc[2][5] = {};

    stageK(0);
    stageV(0, 0);
    __syncthreads();

    int bi = 0;
    for (int kt = 0; kt < S_ / 64; ++kt) {
        const bool more = (kt + 1 < S_ / 64);
        const unsigned long long wq0 = pmq0[kt];
        const unsigned long long wq1 = pmq1[kt];
        if (more) stageV(bi ^ 1, kt + 1);   // V prefetch overlaps QK^T + softmax

        // QK^T + softmax in two mb-halves (keeps sct at 16 regs).
        #pragma unroll
        for (int half = 0; half < 2; ++half) {
            f32x4 sct[2][2] = {};
            __builtin_amdgcn_s_setprio(1);
            #pragma unroll
            for (int s = 0; s < 2; ++s) {
                const int cs = ((s * 4 + quad) ^ xq) * 8;
                #pragma unroll
                for (int mbh = 0; mbh < 2; ++mbh) {
                    bf16x8 ka = *(const bf16x8*)&Ks[((half * 2 + mbh) * 16 + l16) * 64 + cs];
                    sct[mbh][0] = __builtin_amdgcn_mfma_f32_16x16x32_bf16(ka, qa[0][s], sct[mbh][0], 0, 0, 0);
                    sct[mbh][1] = __builtin_amdgcn_mfma_f32_16x16x32_bf16(ka, qa[1][s], sct[mbh][1], 0, 0, 0);
                }
            }
            __builtin_amdgcn_s_setprio(0);

            #pragma unroll
            for (int qf = 0; qf < 2; ++qf) {
                const unsigned long long wq = qf ? wq1 : wq0;
                #pragma unroll
                for (int mbh = 0; mbh < 2; ++mbh) {
                    const int mb = half * 2 + mbh;
                    const unsigned nib = (unsigned)(wq >> (mb * 16 + quad * 4)) & 0xFu;
                    float e[4];
                    #pragma unroll
                    for (int r = 0; r < 4; ++r) {
                        float x = __builtin_amdgcn_exp2f(sct[mbh][qf][r]);
                        e[r] = ((nib >> r) & 1u) ? x : 0.f;
                    }
                    uint2 w;
                    w.x = cvt_pk_bf16(e[0], e[1]);
                    w.y = cvt_pk_bf16(e[2], e[3]);
                    *(uint2*)&Ps[(wave * 32 + qf * 16 + l16) * 64 +
                                 ((mb * 16 + quad * 4) ^ (xq * 8))] = w;
                }
            }
        }

        __syncthreads();                 // all waves done reading Ks
        if (more) stageK(kt + 1);        // K staging overlaps PV

        // PV (+ row-sum via constant ones B): A = P rows (q), B = Vs rows (d)
        __builtin_amdgcn_s_setprio(1);
        #pragma unroll
        for (int s = 0; s < 2; ++s) {
            const int cs = ((s * 4 + quad) ^ xq) * 8;
            bf16x8 pa0 = *(const bf16x8*)&Ps[(wave * 32 + l16) * 64 +
                                             ((s * 32 + quad * 8) ^ (xq * 8))];
            bf16x8 pa1 = *(const bf16x8*)&Ps[(wave * 32 + 16 + l16) * 64 +
                                             ((s * 32 + quad * 8) ^ (xq * 8))];
            #pragma unroll
            for (int db = 0; db < 4; ++db) {
                bf16x8 vb = *(const bf16x8*)&Vs[bi][(db * 16 + l16) * 64 + cs];
                oacc[0][db] = __builtin_amdgcn_mfma_f32_16x16x32_bf16(pa0, vb, oacc[0][db], 0, 0, 0);
                oacc[1][db] = __builtin_amdgcn_mfma_f32_16x16x32_bf16(pa1, vb, oacc[1][db], 0, 0, 0);
            }
            oacc[0][4] = __builtin_amdgcn_mfma_f32_16x16x32_bf16(pa0, vb_ones, oacc[0][4], 0, 0, 0);
            oacc[1][4] = __builtin_amdgcn_mfma_f32_16x16x32_bf16(pa1, vb_ones, oacc[1][4], 0, 0, 0);
        }
        __builtin_amdgcn_s_setprio(0);

        __syncthreads();   // drains K+V staging (vmcnt0) + guards Vs swap
        bi ^= 1;
    }

    // epilogue: lane holds rows q = quad*4+r, cols d = db*16+l16; sum in oacc[qf][4][r]
    #pragma unroll
    for (int qf = 0; qf < 2; ++qf) {
        #pragma unroll
        for (int r = 0; r < 4; ++r) {
            const float linv = 1.0f / oacc[qf][4][r];
            const int qg = q0 + wave * 32 + qf * 16 + quad * 4 + r;
            #pragma unroll
            for (int db = 0; db < 4; ++db) {
                O[(size_t)(b * S_ + qg) * D_ + h * DK_ + db * 16 + l16] =
                    f2bf(oacc[qf][db][r] * linv);
            }
        }
    }
}

extern "C" void kernel_launch(void* const* d_in, const int* in_sizes, int n_in,
                              void* d_out, int out_size, void* d_ws, size_t ws_size,
                              hipStream_t stream)
{
    const float* q   = (const float*)d_in[0];
    const float* k   = (const float*)d_in[1];
    const float* v   = (const float*)d_in[2];
    const int* mask  = (const int*)d_in[3];
    const float* Wq  = (const float*)d_in[4];
    const float* bq  = (const float*)d_in[5];
    const float* Wk  = (const float*)d_in[6];
    const float* bk  = (const float*)d_in[7];
    const float* Wv  = (const float*)d_in[8];
    const float* bv  = (const float*)d_in[9];
    const float* Wo  = (const float*)d_in[10];
    const float* bo  = (const float*)d_in[11];

    const size_t MN = (size_t)B_ * S_ * D_;    // 8.4M elements
    const size_t WN = (size_t)D_ * D_;         // 1M elements
    unsigned short* qb  = (unsigned short*)d_ws;   // bf16 activations
    unsigned short* kb  = qb + MN;
    unsigned short* vb  = kb + MN;
    unsigned short* Qw  = vb + MN;
    unsigned short* Kw  = Qw + MN;
    unsigned short* Vt  = Kw + MN;
    unsigned short* wqb = Vt + MN;   // weights: wqb/wkb/wvb CONTIGUOUS = Wqkv
    unsigned short* wkb = wqb + WN;
    unsigned short* wvb = wkb + WN;
    unsigned short* wob = wvb + WN;
    unsigned short* Ow  = qb;   // qb dead after QKV-GEMM; attn writes Ow after
    // Packed mask (2 MB) in d_out scratch; final GEMM overwrites all of d_out.
    unsigned long long* pm = (unsigned long long*)d_out;

    dim3 blk(256);

    // One fused preprocessing launch: casts (act 12288 blocks, w 2048) + mask
    // pack (2048, grid-strided). Was 3 launches.
    prep_all<<<dim3(16384), blk, 0, stream>>>(
        q, k, v, Wq, Wk, Wv, Wo, mask,
        qb, kb, vb, wqb, wkb, wvb, wob, pm);

    // Q scaled by log2(e)/sqrt(DK) -> attention scores already in exp2 domain
    const float qscale = 1.44269504088896341f * 0.125f;

    gemm_qkv<<<dim3(3 * D_ / 128, (B_ * S_) / 128), blk, 0, stream>>>(
        qb, kb, vb, wqb, bq, bk, bv, Qw, Kw, Vt, qscale);

    attn_kernel<<<dim3(S_ / 128, B_ * H_), blk, 0, stream>>>(Qw, Kw, Vt, pm, Ow);

    gemm_out<<<dim3(D_ / 128, (B_ * S_) / 128), blk, 0, stream>>>(
        Ow, wob, bo, (float*)d_out);
}

// Round 8
// 379.481 us; speedup vs baseline: 1.1091x; 1.0428x over previous
//
#include <hip/hip_runtime.h>

#define B_  4
#define S_  2048
#define D_  1024
#define H_  16
#define DK_ 64

typedef __attribute__((ext_vector_type(8))) __bf16 bf16x8;
typedef __attribute__((ext_vector_type(4))) float  f32x4;

#define AS1 __attribute__((address_space(1)))
#define AS3 __attribute__((address_space(3)))

// Async 16B global -> LDS. Per-lane dest must equal wave-uniform base + lane*16.
__device__ __forceinline__ void gl2lds16(const void* g, void* l) {
    __builtin_amdgcn_global_load_lds((const AS1 unsigned int*)g,
                                     (AS3 unsigned int*)l, 16, 0, 0);
}

__device__ __forceinline__ unsigned short f2bf(float f) {
    union { float f; unsigned u; } v; v.f = f;
    return (unsigned short)((v.u + 0x7FFFu + ((v.u >> 16) & 1u)) >> 16);
}

// hardware packed f32->bf16 (RNE), 1 VALU op for 2 values (T12 primitive;
// verified correct on this harness since R4 — same absmax as manual rounding)
__device__ __forceinline__ unsigned cvt_pk_bf16(float lo, float hi) {
    unsigned r;
    asm("v_cvt_pk_bf16_f32 %0, %1, %2" : "=v"(r) : "v"(lo), "v"(hi));
    return r;
}

__device__ __forceinline__ void cast8(const float* __restrict__ x,
                                      unsigned short* __restrict__ y, int i) {
    float4 a = ((const float4*)x)[2 * i];
    float4 b = ((const float4*)x)[2 * i + 1];
    uint4 w;
    w.x = cvt_pk_bf16(a.x, a.y);
    w.y = cvt_pk_bf16(a.z, a.w);
    w.z = cvt_pk_bf16(b.x, b.y);
    w.w = cvt_pk_bf16(b.z, b.w);
    ((uint4*)y)[i] = w;
}

// All preprocessing in ONE launch: casts (act 12288 blocks, w 2048) + mask
// pack (2048, grid-strided). Branches are block-uniform.
__global__ __launch_bounds__(256) void prep_all(
    const float* __restrict__ q, const float* __restrict__ k,
    const float* __restrict__ v, const float* __restrict__ Wq,
    const float* __restrict__ Wk, const float* __restrict__ Wv,
    const float* __restrict__ Wo, const int* __restrict__ mask,
    unsigned short* __restrict__ qb, unsigned short* __restrict__ kb,
    unsigned short* __restrict__ vb, unsigned short* __restrict__ wqb,
    unsigned short* __restrict__ wkb, unsigned short* __restrict__ wvb,
    unsigned short* __restrict__ wob, unsigned long long* __restrict__ pmo)
{
    const int bid = blockIdx.x;
    if (bid < 12288) {                         // activations: 3 x 4096 blocks
        const int sel = bid >> 12;
        const float* x = (sel == 0) ? q : (sel == 1) ? k : v;
        unsigned short* y = (sel == 0) ? qb : (sel == 1) ? kb : vb;
        cast8(x, y, (bid & 4095) * 256 + threadIdx.x);
    } else if (bid < 14336) {                  // weights: 4 x 512 blocks
        const int b2 = bid - 12288;
        const int sel = b2 >> 9;
        const float* x = (sel == 0) ? Wq : (sel == 1) ? Wk : (sel == 2) ? Wv : Wo;
        unsigned short* y = (sel == 0) ? wqb : (sel == 1) ? wkb : (sel == 2) ? wvb : wob;
        cast8(x, y, (b2 & 511) * 256 + threadIdx.x);
    } else {                                   // mask pack: 2048 blocks, strided
        const int b3 = bid - 14336;
        const int lane = threadIdx.x & 63;
        int w = (b3 * 256 + (int)threadIdx.x) >> 6;     // [0, 8192)
        #pragma unroll 4
        for (int it = 0; it < 32; ++it, w += 8192) {    // 262144 words total
            const int mv = mask[(size_t)w * 64 + lane];
            const unsigned long long bal = __ballot(mv != 0);
            if (lane == 0) pmo[w] = bal;
        }
    }
}

// Fused QKV projection GEMM over N=3072 output cols (Wq;Wk;Wv rows contiguous).
// CRITICAL (R7/R8 bug): each projection has a DIFFERENT A-operand —
// Q = query@Wq, K = key@Wk, V = value@Wv. Selection is block-uniform.
// Within-XCD 2D grouping (4 n-cols x 8 m-rows per group): W-group 1MB +
// A-panel 256KB resident per XCD L2.
__global__ __launch_bounds__(256, 3) void gemm_qkv(
    const unsigned short* __restrict__ Xq, const unsigned short* __restrict__ Xk,
    const unsigned short* __restrict__ Xv, const unsigned short* __restrict__ Wqkv,
    const float* __restrict__ bq, const float* __restrict__ bk,
    const float* __restrict__ bv, unsigned short* __restrict__ Qw,
    unsigned short* __restrict__ Kw, unsigned short* __restrict__ Vt,
    float qscale)
{
    __shared__ unsigned short As[128 * 64];
    __shared__ unsigned short Bs[128 * 64];

    const int tid  = threadIdx.x;
    const int lane = tid & 63, wave = tid >> 6;
    const int l16  = lane & 15, quad = lane >> 4;
    const int wm = wave & 1, wn = wave >> 1;

    // XCD swizzle + 2D grouping: lin in [0,1536); xcd = lin&7; i in [0,192);
    // group ng (6 of 4 n-cols), within group 8 m-rows x 4 n-cols.
    const int lin = blockIdx.y * 24 + blockIdx.x;
    const int xcd = lin & 7;
    const int i   = lin >> 3;
    const int ng  = i >> 5;
    const int r_  = i & 31;
    const int bx  = ng * 4 + (r_ & 3);        // [0,24)
    const int by  = xcd * 8 + (r_ >> 2);      // [0,64)

    const int n0 = bx * 128, m0 = by * 128;
    const int xr = l16 & 7;

    const int sel = bx >> 3;               // 0=Q, 1=K, 2=V (block-uniform)
    const unsigned short* X = (sel == 0) ? Xq : (sel == 1) ? Xk : Xv;

    const int row8 = lane >> 3;
    const int sc   = ((lane & 7) ^ row8) * 8;

    f32x4 acc[4][4] = {};

    for (int k0 = 0; k0 < D_; k0 += 64) {
        __syncthreads();
        #pragma unroll
        for (int j = 0; j < 4; ++j) {
            const int ca = wave * 4 + j;
            const int r  = ca * 8 + row8;
            gl2lds16(X    + (size_t)(m0 + r) * D_ + k0 + sc, &As[ca * 512 + (lane & 63) * 8]);
            gl2lds16(Wqkv + (size_t)(n0 + r) * D_ + k0 + sc, &Bs[ca * 512 + (lane & 63) * 8]);
        }
        __syncthreads();

        #pragma unroll
        for (int s = 0; s < 2; ++s) {
            bf16x8 a[4], bb[4];
            #pragma unroll
            for (int i2 = 0; i2 < 4; ++i2)
                a[i2] = *(const bf16x8*)&As[(wm * 64 + i2 * 16 + l16) * 64 + (((s * 4 + quad) ^ xr)) * 8];
            #pragma unroll
            for (int j = 0; j < 4; ++j)
                bb[j] = *(const bf16x8*)&Bs[(wn * 64 + j * 16 + l16) * 64 + (((s * 4 + quad) ^ xr)) * 8];
            #pragma unroll
            for (int i2 = 0; i2 < 4; ++i2)
                #pragma unroll
                for (int j = 0; j < 4; ++j)
                    acc[i2][j] = __builtin_amdgcn_mfma_f32_16x16x32_bf16(a[i2], bb[j], acc[i2][j], 0, 0, 0);
        }
    }

    const int ncol = (bx & 7) * 128 + wn * 64;   // col base within projection
    const float scale = (sel == 0) ? qscale : 1.0f;
    const float* bias = (sel == 0) ? bq : (sel == 1) ? bk : bv;

    if (sel == 2) {
        // V: transposed per-head write Vt[(b*D+dk)*S+s], packed b64 runs along s
        const int bb_ = m0 >> 11;
        #pragma unroll
        for (int j = 0; j < 4; ++j) {
            const int dk = ncol + j * 16 + l16;
            const float bvv = bias[dk];
            #pragma unroll
            for (int i2 = 0; i2 < 4; ++i2) {
                const int sb = (m0 & (S_ - 1)) + wm * 64 + i2 * 16 + quad * 4;
                uint2 w;
                w.x = cvt_pk_bf16(acc[i2][j][0] + bvv, acc[i2][j][1] + bvv);
                w.y = cvt_pk_bf16(acc[i2][j][2] + bvv, acc[i2][j][3] + bvv);
                *(uint2*)(Vt + (size_t)(bb_ * D_ + dk) * S_ + sb) = w;
            }
        }
    } else {
        unsigned short* Outp = sel ? Kw : Qw;
        #pragma unroll
        for (int j = 0; j < 4; ++j) {
            const int n = ncol + j * 16 + l16;
            const float bvv = bias[n];
            #pragma unroll
            for (int i2 = 0; i2 < 4; ++i2) {
                #pragma unroll
                for (int r = 0; r < 4; ++r) {
                    const int m = m0 + wm * 64 + i2 * 16 + quad * 4 + r;
                    Outp[(size_t)m * D_ + n] = f2bf((acc[i2][j][r] + bvv) * scale);
                }
            }
        }
    }
}

// Output GEMM: C = X * W^T + bias (fp32 out).
// R8: tile 128x128 -> 128x64. Old grid 512 blocks = 2 blocks/CU resident
// (8 waves/CU) — the worst latency hiding in the pipeline. New: grid 1024
// (4/CU), LDS 24KB (96KB@4), acc 32 VGPR -> launch_bounds(256,4) = 16
// waves/CU (2x). W (2MB) fully L2-resident so extra B re-reads are free;
// X-panel stays L2-resident across n-groups (group order: ng outer).
__global__ __launch_bounds__(256, 4) void gemm_out(
    const unsigned short* __restrict__ X, const unsigned short* __restrict__ W,
    const float* __restrict__ bias, float* __restrict__ Out)
{
    __shared__ unsigned short As[128 * 64];
    __shared__ unsigned short Bs[64 * 64];

    const int tid  = threadIdx.x;
    const int lane = tid & 63, wave = tid >> 6;
    const int l16  = lane & 15, quad = lane >> 4;
    const int wm = wave & 1, wn = wave >> 1;

    // XCD swizzle + 2D grouping: lin in [0,1024); 128 blocks/XCD =
    // 4 n-groups (ng) x (4 bx x 8 by). bx in [0,16), by in [0,64).
    const int lin = blockIdx.y * 16 + blockIdx.x;
    const int xcd = lin & 7;
    const int i   = lin >> 3;                     // [0,128)
    const int ng  = i >> 5;                       // [0,4)
    const int r_  = i & 31;
    const int bx  = ng * 4 + (r_ & 3);            // [0,16)
    const int by  = xcd * 8 + (r_ >> 2);          // [0,64)

    const int n0 = bx * 64, m0 = by * 128;
    const int xr = l16 & 7;

    const int row8 = lane >> 3;
    const int sc   = ((lane & 7) ^ row8) * 8;

    f32x4 acc[4][2] = {};

    for (int k0 = 0; k0 < D_; k0 += 64) {
        __syncthreads();
        #pragma unroll
        for (int j = 0; j < 4; ++j) {          // A: 128 rows
            const int ca = wave * 4 + j;
            const int r  = ca * 8 + row8;
            gl2lds16(X + (size_t)(m0 + r) * D_ + k0 + sc, &As[ca * 512 + (lane & 63) * 8]);
        }
        #pragma unroll
        for (int j = 0; j < 2; ++j) {          // B: 64 rows
            const int c = j * 256 + tid;
            const int row = c >> 3;
            const int cl = (c & 7) ^ (row & 7);
            gl2lds16(W + (size_t)(n0 + row) * D_ + k0 + cl * 8, &Bs[c * 8]);
        }
        __syncthreads();

        #pragma unroll
        for (int s = 0; s < 2; ++s) {
            bf16x8 a[4], bb[2];
            #pragma unroll
            for (int i2 = 0; i2 < 4; ++i2)
                a[i2] = *(const bf16x8*)&As[(wm * 64 + i2 * 16 + l16) * 64 + (((s * 4 + quad) ^ xr)) * 8];
            #pragma unroll
            for (int j = 0; j < 2; ++j)
                bb[j] = *(const bf16x8*)&Bs[(wn * 32 + j * 16 + l16) * 64 + (((s * 4 + quad) ^ xr)) * 8];
            #pragma unroll
            for (int i2 = 0; i2 < 4; ++i2)
                #pragma unroll
                for (int j = 0; j < 2; ++j)
                    acc[i2][j] = __builtin_amdgcn_mfma_f32_16x16x32_bf16(a[i2], bb[j], acc[i2][j], 0, 0, 0);
        }
    }

    #pragma unroll
    for (int j = 0; j < 2; ++j) {
        const int n = n0 + wn * 32 + j * 16 + l16;
        const float bv = bias[n];
        #pragma unroll
        for (int i2 = 0; i2 < 4; ++i2) {
            #pragma unroll
            for (int r = 0; r < 4; ++r) {
                const int m = m0 + wm * 64 + i2 * 16 + quad * 4 + r;
                Out[(size_t)m * D_ + n] = acc[i2][j][r] + bv;
            }
        }
    }
}

// Flash attention, transposed-score, fixed-max softmax, MFMA row-sums.
// R5 structure (best measured: 104.3 us), unchanged — control kernel.
// QBLK=128 (wave owns 32 q rows), KVBLK=64; LDS 40KB = Ks 8K (single-buf,
// staged under PV after mid barrier) + Vs 2x8K (dbuf) + Ps 16K -> 4
// blocks/CU, grid 1024 = exactly one fully-resident round.
__global__ __launch_bounds__(256, 4) void attn_kernel(
    const unsigned short* __restrict__ Q,
    const unsigned short* __restrict__ Kg,
    const unsigned short* __restrict__ Vt,
    const unsigned long long* __restrict__ pm,
    unsigned short* __restrict__ O)
{
    __shared__ unsigned short Ks[64 * 64];
    __shared__ unsigned short Vs[2][64 * 64];
    __shared__ unsigned short Ps[128 * 64];

    const int tid  = threadIdx.x;
    const int lane = tid & 63, wave = tid >> 6;
    const int l16  = lane & 15, quad = lane >> 4;

    // XCD-chunked swizzle (bijective: 1024 % 8 == 0). gridDim = (16, 64).
    const int n  = blockIdx.y * 16 + blockIdx.x;
    const int ns = (n & 7) * 128 + (n >> 3);
    const int b  = ns >> 8;
    const int h  = (ns >> 4) & 15;
    const int q0 = (ns & 15) * 128;
    const int xq = l16 & 7;

    // all-ones B operand for the row-sum MFMA
    union { uint4 u; bf16x8 v; } ones_u;
    ones_u.u = make_uint4(0x3F803F80u, 0x3F803F80u, 0x3F803F80u, 0x3F803F80u);
    const bf16x8 vb_ones = ones_u.v;

    // Q fragments: qa[qf][s], wave owns q rows q0 + wave*32 + qf*16 + l16
    bf16x8 qa[2][2];
    #pragma unroll
    for (int qf = 0; qf < 2; ++qf) {
        const unsigned short* qp =
            Q + (size_t)(b * S_ + q0 + wave * 32 + qf * 16 + l16) * D_ + h * DK_ + quad * 8;
        qa[qf][0] = *(const bf16x8*)qp;
        qa[qf][1] = *(const bf16x8*)(qp + 32);
    }

    const unsigned short* Kbase = Kg + (size_t)(b * S_) * D_ + h * DK_;
    const unsigned short* Vbase = Vt + (size_t)(b * D_ + h * DK_) * S_;

    auto stageK = [&](int kt2) {
        const int k0 = kt2 * 64;
        #pragma unroll
        for (int j = 0; j < 2; ++j) {
            const int c = j * 256 + tid;
            const int row = c >> 3;
            const int cl = (c & 7) ^ (row & 7);
            gl2lds16(Kbase + (size_t)(k0 + row) * D_ + cl * 8, &Ks[c * 8]);
        }
    };
    auto stageV = [&](int bi2, int kt2) {
        const int k0 = kt2 * 64;
        #pragma unroll
        for (int j = 0; j < 2; ++j) {
            const int c = j * 256 + tid;
            const int row = c >> 3;
            const int cl = (c & 7) ^ (row & 7);
            gl2lds16(Vbase + (size_t)row * S_ + k0 + cl * 8, &Vs[bi2][c * 8]);
        }
    };

    const unsigned long long* pmq0 =
        pm + (size_t)(b * S_ + q0 + wave * 32 + l16) * (S_ / 64);
    const unsigned long long* pmq1 = pmq0 + (size_t)16 * (S_ / 64);

    f32x4 oacc[2][5] = {};

    stageK(0);
    stageV(0, 0);
    __syncthreads();

    int bi = 0;
    for (int kt = 0; kt < S_ / 64; ++kt) {
        const bool more = (kt + 1 < S_ / 64);
        const unsigned long long wq0 = pmq0[kt];
        const unsigned long long wq1 = pmq1[kt];
        if (more) stageV(bi ^ 1, kt + 1);   // V prefetch overlaps QK^T + softmax

        // QK^T + softmax in two mb-halves (keeps sct at 16 regs).
        #pragma unroll
        for (int half = 0; half < 2; ++half) {
            f32x4 sct[2][2] = {};
            __builtin_amdgcn_s_setprio(1);
            #pragma unroll
            for (int s = 0; s < 2; ++s) {
                const int cs = ((s * 4 + quad) ^ xq) * 8;
                #pragma unroll
                for (int mbh = 0; mbh < 2; ++mbh) {
                    bf16x8 ka = *(const bf16x8*)&Ks[((half * 2 + mbh) * 16 + l16) * 64 + cs];
                    sct[mbh][0] = __builtin_amdgcn_mfma_f32_16x16x32_bf16(ka, qa[0][s], sct[mbh][0], 0, 0, 0);
                    sct[mbh][1] = __builtin_amdgcn_mfma_f32_16x16x32_bf16(ka, qa[1][s], sct[mbh][1], 0, 0, 0);
                }
            }
            __builtin_amdgcn_s_setprio(0);

            #pragma unroll
            for (int qf = 0; qf < 2; ++qf) {
                const unsigned long long wq = qf ? wq1 : wq0;
                #pragma unroll
                for (int mbh = 0; mbh < 2; ++mbh) {
                    const int mb = half * 2 + mbh;
                    const unsigned nib = (unsigned)(wq >> (mb * 16 + quad * 4)) & 0xFu;
                    float e[4];
                    #pragma unroll
                    for (int r = 0; r < 4; ++r) {
                        float x = __builtin_amdgcn_exp2f(sct[mbh][qf][r]);
                        e[r] = ((nib >> r) & 1u) ? x : 0.f;
                    }
                    uint2 w;
                    w.x = cvt_pk_bf16(e[0], e[1]);
                    w.y = cvt_pk_bf16(e[2], e[3]);
                    *(uint2*)&Ps[(wave * 32 + qf * 16 + l16) * 64 +
                                 ((mb * 16 + quad * 4) ^ (xq * 8))] = w;
                }
            }
        }

        __syncthreads();                 // all waves done reading Ks
        if (more) stageK(kt + 1);        // K staging overlaps PV

        // PV (+ row-sum via constant ones B): A = P rows (q), B = Vs rows (d)
        __builtin_amdgcn_s_setprio(1);
        #pragma unroll
        for (int s = 0; s < 2; ++s) {
            const int cs = ((s * 4 + quad) ^ xq) * 8;
            bf16x8 pa0 = *(const bf16x8*)&Ps[(wave * 32 + l16) * 64 +
                                             ((s * 32 + quad * 8) ^ (xq * 8))];
            bf16x8 pa1 = *(const bf16x8*)&Ps[(wave * 32 + 16 + l16) * 64 +
                                             ((s * 32 + quad * 8) ^ (xq * 8))];
            #pragma unroll
            for (int db = 0; db < 4; ++db) {
                bf16x8 vb = *(const bf16x8*)&Vs[bi][(db * 16 + l16) * 64 + cs];
                oacc[0][db] = __builtin_amdgcn_mfma_f32_16x16x32_bf16(pa0, vb, oacc[0][db], 0, 0, 0);
                oacc[1][db] = __builtin_amdgcn_mfma_f32_16x16x32_bf16(pa1, vb, oacc[1][db], 0, 0, 0);
            }
            oacc[0][4] = __builtin_amdgcn_mfma_f32_16x16x32_bf16(pa0, vb_ones, oacc[0][4], 0, 0, 0);
            oacc[1][4] = __builtin_amdgcn_mfma_f32_16x16x32_bf16(pa1, vb_ones, oacc[1][4], 0, 0, 0);
        }
        __builtin_amdgcn_s_setprio(0);

        __syncthreads();   // drains K+V staging (vmcnt0) + guards Vs swap
        bi ^= 1;
    }

    // epilogue: lane holds rows q = quad*4+r, cols d = db*16+l16; sum in oacc[qf][4][r]
    #pragma unroll
    for (int qf = 0; qf < 2; ++qf) {
        #pragma unroll
        for (int r = 0; r < 4; ++r) {
            const float linv = 1.0f / oacc[qf][4][r];
            const int qg = q0 + wave * 32 + qf * 16 + quad * 4 + r;
            #pragma unroll
            for (int db = 0; db < 4; ++db) {
                O[(size_t)(b * S_ + qg) * D_ + h * DK_ + db * 16 + l16] =
                    f2bf(oacc[qf][db][r] * linv);
            }
        }
    }
}

extern "C" void kernel_launch(void* const* d_in, const int* in_sizes, int n_in,
                              void* d_out, int out_size, void* d_ws, size_t ws_size,
                              hipStream_t stream)
{
    const float* q   = (const float*)d_in[0];
    const float* k   = (const float*)d_in[1];
    const float* v   = (const float*)d_in[2];
    const int* mask  = (const int*)d_in[3];
    const float* Wq  = (const float*)d_in[4];
    const float* bq  = (const float*)d_in[5];
    const float* Wk  = (const float*)d_in[6];
    const float* bk  = (const float*)d_in[7];
    const float* Wv  = (const float*)d_in[8];
    const float* bv  = (const float*)d_in[9];
    const float* Wo  = (const float*)d_in[10];
    const float* bo  = (const float*)d_in[11];

    const size_t MN = (size_t)B_ * S_ * D_;    // 8.4M elements
    const size_t WN = (size_t)D_ * D_;         // 1M elements
    unsigned short* qb  = (unsigned short*)d_ws;   // bf16 activations
    unsigned short* kb  = qb + MN;
    unsigned short* vb  = kb + MN;
    unsigned short* Qw  = vb + MN;
    unsigned short* Kw  = Qw + MN;
    unsigned short* Vt  = Kw + MN;
    unsigned short* wqb = Vt + MN;   // weights: wqb/wkb/wvb CONTIGUOUS = Wqkv
    unsigned short* wkb = wqb + WN;
    unsigned short* wvb = wkb + WN;
    unsigned short* wob = wvb + WN;
    unsigned short* Ow  = qb;   // qb dead after QKV-GEMM; attn writes Ow after
    // Packed mask (2 MB) in d_out scratch; final GEMM overwrites all of d_out.
    unsigned long long* pm = (unsigned long long*)d_out;

    dim3 blk(256);

    // One fused preprocessing launch: casts (act 12288 blocks, w 2048) + mask
    // pack (2048, grid-strided).
    prep_all<<<dim3(16384), blk, 0, stream>>>(
        q, k, v, Wq, Wk, Wv, Wo, mask,
        qb, kb, vb, wqb, wkb, wvb, wob, pm);

    // Q scaled by log2(e)/sqrt(DK) -> attention scores already in exp2 domain
    const float qscale = 1.44269504088896341f * 0.125f;

    gemm_qkv<<<dim3(3 * D_ / 128, (B_ * S_) / 128), blk, 0, stream>>>(
        qb, kb, vb, wqb, bq, bk, bv, Qw, Kw, Vt, qscale);

    attn_kernel<<<dim3(S_ / 128, B_ * H_), blk, 0, stream>>>(Qw, Kw, Vt, pm, Ow);

    gemm_out<<<dim3(D_ / 64, (B_ * S_) / 128), blk, 0, stream>>>(
        Ow, wob, bo, (float*)d_out);
}